// Round 9
// baseline (763.399 us; speedup 1.0000x reference)
//
#include <hip/hip_runtime.h>

#define SZ 128
#define NATOMS 100000
#define NBONDS 400000
#define NPAIRS 400000
#define NANG   800000

typedef float f32x4 __attribute__((ext_vector_type(4)));
typedef short s16x8 __attribute__((ext_vector_type(8)));

__device__ __forceinline__ unsigned short f2bf(float f) {
  union { float f; unsigned u; } v; v.f = f;
  unsigned r = v.u + 0x7FFFu + ((v.u >> 16) & 1u);
  return (unsigned short)(r >> 16);
}
__device__ __forceinline__ float bf2f(unsigned short h) {
  union { unsigned u; float f; } v; v.u = ((unsigned)h) << 16;
  return v.f;
}

// ---- workspace layout (bytes) ----
#define AGG_OFF      0ull
#define AGG2_OFF     51200000ull
#define CNT_OFF      102400000ull
#define FILL_OFF     104000000ull
#define CNTB_OFF     105600000ull
#define FILLB_OFF    106000000ull
#define CNTP_OFF     106400000ull
#define FILLP_OFF    106800000ull
#define ZERO_BYTES   107200000ull
#define START_OFF    107200000ull
#define ALIST_OFF    108800000ull
#define BSUM_OFF     112000000ull
#define STARTB_OFF   112004096ull
#define BLIST_OFF    112404096ull
#define DLIST_OFF    114004096ull
#define BSUMB_OFF    115604096ull
#define STARTP_OFF   115608192ull
#define PLIST_OFF    116008192ull
#define ILIST_OFF    117608192ull
#define BSUMP_OFF    119208192ull
#define DESC1_OFF    119212288ull   // 400K x 32B
#define DESC2_OFF    132012288ull   // 400K x 16B
#define H_OFF        138412288ull
#define H2_OFF       164012288ull
#define WT_BM_OFF    189612288ull
#define WT_SC_OFF    (WT_BM_OFF + 32768ull)
#define WT1_OFF      (WT_SC_OFF + 32768ull)
#define WT2_OFF      (WT1_OFF + 32768ull)
#define COMB_OFF     189744128ull   // 400K x 256B bf16 (shared by msg1/msg2)

#define SCAN_EPB 1024

// Zero exactly ZERO_BYTES of ws with wide stores (replaces hipMemsetAsync whose
// fill dispatch was observed writing 1.6 GB / ~240 us per replay).
__global__ __launch_bounds__(256) void k_zero(uint4* __restrict__ p, size_t n16) {
  size_t id = (size_t)blockIdx.x * 256 + threadIdx.x;
  size_t stride = (size_t)gridDim.x * 256;
  uint4 z = {0u, 0u, 0u, 0u};
  for (size_t i = id; i < n16; i += stride) p[i] = z;
}

// Pack W (f32 [k][n]) into bf16 B-fragment order.
__global__ __launch_bounds__(256) void k_prep_w(const float* __restrict__ W,
                                                s16x8* __restrict__ Wt) {
  int cid = blockIdx.x * 256 + threadIdx.x;
  int nt8 = cid >> 8, kk = (cid >> 6) & 3, l = cid & 63;
  int col = nt8 * 16 + (l & 15);
  int k0  = kk * 32 + (l >> 4) * 8;
  s16x8 v;
#pragma unroll
  for (int i = 0; i < 8; ++i) v[i] = (short)f2bf(W[(k0 + i) * SZ + col]);
  Wt[cid] = v;
}

// LayerNorm f32 -> bf16
__global__ __launch_bounds__(256) void k_ln(const float* __restrict__ x,
                                            const float* __restrict__ g,
                                            const float* __restrict__ bvec,
                                            unsigned short* __restrict__ hout) {
  int row  = blockIdx.x * 4 + (threadIdx.x >> 6);
  int lane = threadIdx.x & 63;
  float2 v = *(const float2*)(x + (size_t)row * SZ + lane * 2);
  float s = v.x + v.y, sq = v.x * v.x + v.y * v.y;
#pragma unroll
  for (int off = 32; off; off >>= 1) { s += __shfl_xor(s, off); sq += __shfl_xor(sq, off); }
  float m = s * 0.0078125f;
  float var = sq * 0.0078125f - m * m;
  float rstd = rsqrtf(var + 1e-5f);
  float2 gv = *(const float2*)(g + lane * 2);
  float2 bv = *(const float2*)(bvec + lane * 2);
  float y0 = (v.x - m) * rstd * gv.x + bv.x;
  float y1 = (v.y - m) * rstd * gv.y + bv.y;
  unsigned pack = (unsigned)f2bf(y0) | ((unsigned)f2bf(y1) << 16);
  ((unsigned*)hout)[(size_t)row * 64 + lane] = pack;
}

// ---- generic CSR build ----
__global__ __launch_bounds__(256) void k_hist(const int* __restrict__ idx, int n,
                                              int stride, int off,
                                              int* __restrict__ cnt) {
  int id = blockIdx.x * 256 + threadIdx.x;
  if (id < n) atomicAdd(&cnt[idx[id * stride + off]], 1);
}

__global__ __launch_bounds__(256) void k_scan1(const int* __restrict__ cnt,
                                               int* __restrict__ start,
                                               int* __restrict__ bsum, int N) {
  __shared__ int wsum[4];
  int tid = threadIdx.x, bid = blockIdx.x;
  int base = bid * SCAN_EPB + tid * 4;
  int4 c;
  if (base + 3 < N) {
    c = *(const int4*)(cnt + base);
  } else {
    c.x = (base + 0 < N) ? cnt[base + 0] : 0;
    c.y = (base + 1 < N) ? cnt[base + 1] : 0;
    c.z = (base + 2 < N) ? cnt[base + 2] : 0;
    c.w = (base + 3 < N) ? cnt[base + 3] : 0;
  }
  int tsum = c.x + c.y + c.z + c.w;
  int lane = tid & 63, wid = tid >> 6;
  int inc = tsum;
#pragma unroll
  for (int off = 1; off < 64; off <<= 1) {
    int o = __shfl_up(inc, off);
    if (lane >= off) inc += o;
  }
  if (lane == 63) wsum[wid] = inc;
  __syncthreads();
  int woff = 0;
#pragma unroll
  for (int wq = 0; wq < 4; ++wq) { if (wq < wid) woff += wsum[wq]; }
  int s0 = woff + inc - tsum;
  if (base + 0 < N) { start[base + 0] = s0; } s0 += c.x;
  if (base + 1 < N) { start[base + 1] = s0; } s0 += c.y;
  if (base + 2 < N) { start[base + 2] = s0; } s0 += c.z;
  if (base + 3 < N) { start[base + 3] = s0; }
  if (tid == 255) {
    int tot = 0;
#pragma unroll
    for (int wq = 0; wq < 4; ++wq) tot += wsum[wq];
    bsum[bid] = tot;
  }
}

__global__ __launch_bounds__(512) void k_scan2(int* __restrict__ bsum, int n) {
  __shared__ int tmp[2][512];
  int tid = threadIdx.x;
  tmp[0][tid] = (tid < n) ? bsum[tid] : 0;
  int pi = 0;
  for (int off = 1; off < 512; off <<= 1) {
    __syncthreads();
    int t = tmp[pi][tid];
    if (tid >= off) t += tmp[pi][tid - off];
    tmp[pi ^ 1][tid] = t;
    pi ^= 1;
  }
  __syncthreads();
  if (tid < n) bsum[tid] = (tid == 0) ? 0 : tmp[pi][tid - 1];
}

__global__ __launch_bounds__(256) void k_scan_add(int* __restrict__ start,
                                                  const int* __restrict__ bsum, int N) {
  int id = blockIdx.x * 256 + threadIdx.x;
  if (id < N) start[id] += bsum[id / SCAN_EPB];
}

__global__ __launch_bounds__(256) void k_fill(const int* __restrict__ idx, int n,
                                              int stride, int off,
                                              const int* __restrict__ start,
                                              int* __restrict__ fill,
                                              int* __restrict__ list,
                                              int* __restrict__ klist) {
  int id = blockIdx.x * 256 + threadIdx.x;
  if (id < n) {
    int k = idx[id * stride + off];
    int p = atomicAdd(&fill[k], 1);
    int pos = start[k] + p;
    list[pos] = id;
    if (klist) klist[pos] = k;
  }
}

// desc1[pos] = {b, src, s0, nc, a0, a1, a2, a3}  (dst-sorted positions)
__global__ __launch_bounds__(256) void k_packb(const int* __restrict__ blist,
                                               const int* __restrict__ bidx,
                                               const int* __restrict__ start,
                                               const int* __restrict__ cnt,
                                               const int* __restrict__ alist,
                                               int* __restrict__ desc) {
  int pos = blockIdx.x * 256 + threadIdx.x;
  if (pos >= NBONDS) return;
  int b = blist[pos];
  int4 dA, dB;
  dA.x = b;
  dA.y = bidx[2 * b];
  int s0 = start[b];
  int nc = cnt[b];
  dA.z = s0;
  dA.w = nc;
  dB.x = (0 < nc) ? alist[s0 + 0] : 0;
  dB.y = (1 < nc) ? alist[s0 + 1] : 0;
  dB.z = (2 < nc) ? alist[s0 + 2] : 0;
  dB.w = (3 < nc) ? alist[s0 + 3] : 0;
  *(int4*)(desc + (size_t)pos * 8)     = dA;
  *(int4*)(desc + (size_t)pos * 8 + 4) = dB;
}

// desc2[pos] = {b, i, j, 0}  (i-sorted positions)
__global__ __launch_bounds__(256) void k_packp(const int* __restrict__ plist,
                                               const int* __restrict__ ilist,
                                               const int* __restrict__ sidx,
                                               int* __restrict__ desc) {
  int pos = blockIdx.x * 256 + threadIdx.x;
  if (pos >= NPAIRS) return;
  int b = plist[pos];
  int4 d;
  d.x = b;
  d.y = ilist[pos];
  d.z = sidx[2 * b + 1];
  d.w = 0;
  *(int4*)(desc + (size_t)pos * 4) = d;
}

// Pass A1: comb[pos] = bf16(h[src] + bond_x[b] + sum(angles))  -- pure streaming gather.
__global__ __launch_bounds__(256) void k_gather1(const unsigned short* __restrict__ h,
                                                 const float* __restrict__ bx,
                                                 const float* __restrict__ angles,
                                                 const int* __restrict__ alist,
                                                 const int* __restrict__ desc,
                                                 unsigned short* __restrict__ comb) {
  int id = blockIdx.x * 256 + threadIdx.x;   // NBONDS*16 threads exactly
  int pos = id >> 4, kc = id & 15;
  int4 dA = *(const int4*)(desc + (size_t)pos * 8);
  int4 dB = *(const int4*)(desc + (size_t)pos * 8 + 4);
  int b = dA.x, src = dA.y, s0 = dA.z, nc = dA.w;
  const int co = kc * 8;
  float a[8];
  *(float4*)&a[0] = *(const float4*)(bx + (size_t)b * SZ + co);
  *(float4*)&a[4] = *(const float4*)(bx + (size_t)b * SZ + co + 4);
  uint4 hv = *(const uint4*)(h + (size_t)src * SZ + co);
  int aj[4] = {dB.x, dB.y, dB.z, dB.w};
#pragma unroll
  for (int t = 0; t < 4; ++t) {
    if (t < nc) {
      const float* ap = angles + (size_t)aj[t] * SZ + co;
      float4 u0 = *(const float4*)ap;
      float4 u1 = *(const float4*)(ap + 4);
      a[0] += u0.x; a[1] += u0.y; a[2] += u0.z; a[3] += u0.w;
      a[4] += u1.x; a[5] += u1.y; a[6] += u1.z; a[7] += u1.w;
    }
  }
  for (int t = 4; t < nc; ++t) {
    int ar = alist[s0 + t];
    const float* ap = angles + (size_t)ar * SZ + co;
    float4 u0 = *(const float4*)ap;
    float4 u1 = *(const float4*)(ap + 4);
    a[0] += u0.x; a[1] += u0.y; a[2] += u0.z; a[3] += u0.w;
    a[4] += u1.x; a[5] += u1.y; a[6] += u1.z; a[7] += u1.w;
  }
  const unsigned short* hp = (const unsigned short*)&hv;
  uint4 r;
  unsigned* rp = (unsigned*)&r;
#pragma unroll
  for (int i = 0; i < 4; ++i) {
    unsigned lo = f2bf(bf2f(hp[2 * i]) + a[2 * i]);
    unsigned hi = f2bf(bf2f(hp[2 * i + 1]) + a[2 * i + 1]);
    rp[i] = lo | (hi << 16);
  }
  *(uint4*)(comb + (size_t)pos * SZ + co) = r;
}

// Pass A2: comb[pos] = bf16(h2[i] + h2[j] + sc_pair[b])
__global__ __launch_bounds__(256) void k_gather2(const unsigned short* __restrict__ h2,
                                                 const float* __restrict__ scp,
                                                 const int* __restrict__ desc,
                                                 unsigned short* __restrict__ comb) {
  int id = blockIdx.x * 256 + threadIdx.x;   // NPAIRS*16 threads exactly
  int pos = id >> 4, kc = id & 15;
  int4 d = *(const int4*)(desc + (size_t)pos * 4);
  int b = d.x, i0 = d.y, j0 = d.z;
  const int co = kc * 8;
  float a[8];
  *(float4*)&a[0] = *(const float4*)(scp + (size_t)b * SZ + co);
  *(float4*)&a[4] = *(const float4*)(scp + (size_t)b * SZ + co + 4);
  uint4 hv1 = *(const uint4*)(h2 + (size_t)i0 * SZ + co);
  uint4 hv2 = *(const uint4*)(h2 + (size_t)j0 * SZ + co);
  const unsigned short* p1 = (const unsigned short*)&hv1;
  const unsigned short* p2 = (const unsigned short*)&hv2;
  uint4 r;
  unsigned* rp = (unsigned*)&r;
#pragma unroll
  for (int i = 0; i < 4; ++i) {
    unsigned lo = f2bf(bf2f(p1[2 * i]) + bf2f(p2[2 * i]) + a[2 * i]);
    unsigned hi = f2bf(bf2f(p1[2 * i + 1]) + bf2f(p2[2 * i + 1]) + a[2 * i + 1]);
    rp[i] = lo | (hi << 16);
  }
  *(uint4*)(comb + (size_t)pos * SZ + co) = r;
}

// Pass B: dense GEMM over sorted comb rows + run-combined relu atomic scatter.
__global__ __launch_bounds__(256) void k_gemm_scatter(const unsigned short* __restrict__ comb,
                                                      const int* __restrict__ klist,
                                                      const s16x8* __restrict__ Wt,
                                                      float* __restrict__ aggout) {
  __shared__ s16x8 Wl[2048];   // 32KB B-fragment order
  int tid = threadIdx.x;
  for (int i = tid; i < 2048; i += 256) Wl[i] = Wt[i];
  __syncthreads();
  int w = tid >> 6, l = tid & 63;
  int grp = l >> 4;
  int rl  = l & 15;
  int gw = blockIdx.x * 4 + w;
  int nw = gridDim.x * 4;
  for (int tile = gw; tile < NBONDS / 16; tile += nw) {
    int base = tile * 16;
    f32x4 acc[8];
#pragma unroll
    for (int nb = 0; nb < 8; ++nb) acc[nb] = (f32x4){0.f, 0.f, 0.f, 0.f};
#pragma unroll
    for (int kk = 0; kk < 4; ++kk) {
      const int co = kk * 32 + grp * 8;
      s16x8 av = *(const s16x8*)(comb + (size_t)(base + rl) * SZ + co);
#pragma unroll
      for (int nb = 0; nb < 8; ++nb)
        acc[nb] = __builtin_amdgcn_mfma_f32_16x16x32_bf16(av, Wl[(nb * 4 + kk) * 64 + l], acc[nb], 0, 0, 0);
    }
    int4 dv = *(const int4*)(klist + base + grp * 4);
    int dn[4] = {dv.x, dv.y, dv.z, dv.w};
    float v[8];
#pragma unroll
    for (int nb = 0; nb < 8; ++nb) v[nb] = fmaxf(acc[nb][0], 0.f);
    int dprev = dn[0];
#pragma unroll
    for (int p = 1; p < 4; ++p) {
      if (dn[p] == dprev) {
#pragma unroll
        for (int nb = 0; nb < 8; ++nb) v[nb] += fmaxf(acc[nb][p], 0.f);
      } else {
        float* pb = aggout + (size_t)dprev * SZ + rl;
#pragma unroll
        for (int nb = 0; nb < 8; ++nb) unsafeAtomicAdd(pb + nb * 16, v[nb]);
#pragma unroll
        for (int nb = 0; nb < 8; ++nb) v[nb] = fmaxf(acc[nb][p], 0.f);
        dprev = dn[p];
      }
    }
    float* pb = aggout + (size_t)dprev * SZ + rl;
#pragma unroll
    for (int nb = 0; nb < 8; ++nb) unsafeAtomicAdd(pb + nb * 16, v[nb]);
  }
}

// update1: out = x + agg@W1 + b1 ; h2 = LN(out)
__global__ __launch_bounds__(256) void k_update1(const float* __restrict__ agg,
                                                 const float* __restrict__ x,
                                                 const float* __restrict__ b1,
                                                 const float* __restrict__ lnw,
                                                 const float* __restrict__ lnb,
                                                 const s16x8* __restrict__ Wt,
                                                 float* __restrict__ out,
                                                 unsigned short* __restrict__ h2) {
  __shared__ s16x8 Wl[2048];
  __shared__ s16x8 Tl[256];
  __shared__ float Xl[16][128];
  int tid = threadIdx.x;
  for (int i = tid; i < 2048; i += 256) Wl[i] = Wt[i];
  __syncthreads();
  int r = tid >> 4, kc = tid & 15;
  int w = tid >> 6, l = tid & 63;
  int colb = w * 32 + (l & 15);
  int rowb = (l >> 4) * 4;
  float bb0 = b1[colb], bb1 = b1[colb + 16];
  float2 g2 = *(const float2*)(lnw + l * 2);
  float2 be2 = *(const float2*)(lnb + l * 2);
  for (int tile = blockIdx.x; tile < NATOMS / 16; tile += gridDim.x) {
    int base = tile * 16;
    int a = base + r;
    float qb[8];
    *(float4*)&qb[0] = *(const float4*)(agg + (size_t)a * SZ + kc * 8);
    *(float4*)&qb[4] = *(const float4*)(agg + (size_t)a * SZ + kc * 8 + 4);
    s16x8 tv;
#pragma unroll
    for (int i = 0; i < 8; ++i) tv[i] = (short)f2bf(qb[i]);
    Tl[(kc >> 2) * 64 + (kc & 3) * 16 + r] = tv;
    __syncthreads();
    f32x4 acc0 = {0.f, 0.f, 0.f, 0.f}, acc1 = {0.f, 0.f, 0.f, 0.f};
#pragma unroll
    for (int kk = 0; kk < 4; ++kk) {
      s16x8 av = Tl[kk * 64 + l];
      acc0 = __builtin_amdgcn_mfma_f32_16x16x32_bf16(av, Wl[((w * 2 + 0) * 4 + kk) * 64 + l], acc0, 0, 0, 0);
      acc1 = __builtin_amdgcn_mfma_f32_16x16x32_bf16(av, Wl[((w * 2 + 1) * 4 + kk) * 64 + l], acc1, 0, 0, 0);
    }
#pragma unroll
    for (int p = 0; p < 4; ++p) {
      int atom = base + rowb + p;
      float v0 = acc0[p] + bb0 + x[(size_t)atom * SZ + colb];
      float v1 = acc1[p] + bb1 + x[(size_t)atom * SZ + colb + 16];
      out[(size_t)atom * SZ + colb] = v0;
      out[(size_t)atom * SZ + colb + 16] = v1;
      Xl[rowb + p][colb] = v0;
      Xl[rowb + p][colb + 16] = v1;
    }
    __syncthreads();
#pragma unroll
    for (int rr = 0; rr < 4; ++rr) {
      int rw = w * 4 + rr;
      float2 v = *(const float2*)&Xl[rw][l * 2];
      float s = v.x + v.y, sq = v.x * v.x + v.y * v.y;
#pragma unroll
      for (int off = 32; off; off >>= 1) { s += __shfl_xor(s, off); sq += __shfl_xor(sq, off); }
      float m = s * 0.0078125f;
      float var = sq * 0.0078125f - m * m;
      float rstd = rsqrtf(var + 1e-5f);
      float y0 = (v.x - m) * rstd * g2.x + be2.x;
      float y1 = (v.y - m) * rstd * g2.y + be2.y;
      unsigned pack = (unsigned)f2bf(y0) | ((unsigned)f2bf(y1) << 16);
      ((unsigned*)h2)[(size_t)(base + rw) * 64 + l] = pack;
    }
    __syncthreads();
  }
}

// update2: out += agg2@W2 + b2
__global__ __launch_bounds__(256) void k_update2(const float* __restrict__ agg2,
                                                 const float* __restrict__ b2,
                                                 const s16x8* __restrict__ Wt,
                                                 float* __restrict__ out) {
  __shared__ s16x8 Wl[2048];
  __shared__ s16x8 Tl[256];
  int tid = threadIdx.x;
  for (int i = tid; i < 2048; i += 256) Wl[i] = Wt[i];
  __syncthreads();
  int r = tid >> 4, kc = tid & 15;
  int w = tid >> 6, l = tid & 63;
  int colb = w * 32 + (l & 15);
  int rowb = (l >> 4) * 4;
  float bb0 = b2[colb], bb1 = b2[colb + 16];
  for (int tile = blockIdx.x; tile < NATOMS / 16; tile += gridDim.x) {
    int base = tile * 16;
    int a = base + r;
    float qb[8];
    *(float4*)&qb[0] = *(const float4*)(agg2 + (size_t)a * SZ + kc * 8);
    *(float4*)&qb[4] = *(const float4*)(agg2 + (size_t)a * SZ + kc * 8 + 4);
    s16x8 tv;
#pragma unroll
    for (int i = 0; i < 8; ++i) tv[i] = (short)f2bf(qb[i]);
    Tl[(kc >> 2) * 64 + (kc & 3) * 16 + r] = tv;
    __syncthreads();
    f32x4 acc0 = {0.f, 0.f, 0.f, 0.f}, acc1 = {0.f, 0.f, 0.f, 0.f};
#pragma unroll
    for (int kk = 0; kk < 4; ++kk) {
      s16x8 av = Tl[kk * 64 + l];
      acc0 = __builtin_amdgcn_mfma_f32_16x16x32_bf16(av, Wl[((w * 2 + 0) * 4 + kk) * 64 + l], acc0, 0, 0, 0);
      acc1 = __builtin_amdgcn_mfma_f32_16x16x32_bf16(av, Wl[((w * 2 + 1) * 4 + kk) * 64 + l], acc1, 0, 0, 0);
    }
#pragma unroll
    for (int p = 0; p < 4; ++p) {
      int atom = base + rowb + p;
      out[(size_t)atom * SZ + colb]      += acc0[p] + bb0;
      out[(size_t)atom * SZ + colb + 16] += acc1[p] + bb1;
    }
    __syncthreads();
  }
}

extern "C" void kernel_launch(void* const* d_in, const int* in_sizes, int n_in,
                              void* d_out, int out_size, void* d_ws, size_t ws_size,
                              hipStream_t stream) {
  (void)in_sizes; (void)n_in; (void)out_size; (void)ws_size;
  const float* x        = (const float*)d_in[0];
  const float* bond_x   = (const float*)d_in[1];
  const float* sc_pair  = (const float*)d_in[2];
  const float* angles   = (const float*)d_in[3];
  const float* W_bm     = (const float*)d_in[4];
  const float* W_sc     = (const float*)d_in[5];
  const float* W1       = (const float*)d_in[6];
  const float* b1       = (const float*)d_in[7];
  const float* W2       = (const float*)d_in[8];
  const float* b2       = (const float*)d_in[9];
  const float* ln1w     = (const float*)d_in[10];
  const float* ln1b     = (const float*)d_in[11];
  const float* ln2w     = (const float*)d_in[12];
  const float* ln2b     = (const float*)d_in[13];
  const int* bond_idx   = (const int*)d_in[15];
  const int* sc_idx     = (const int*)d_in[16];
  const int* ang_idx    = (const int*)d_in[17];
  float* out = (float*)d_out;
  char* ws = (char*)d_ws;

  float* agg      = (float*)(ws + AGG_OFF);
  float* agg2     = (float*)(ws + AGG2_OFF);
  int*   cnt      = (int*)(ws + CNT_OFF);
  int*   fill     = (int*)(ws + FILL_OFF);
  int*   cntb     = (int*)(ws + CNTB_OFF);
  int*   fillb    = (int*)(ws + FILLB_OFF);
  int*   cntp     = (int*)(ws + CNTP_OFF);
  int*   fillp    = (int*)(ws + FILLP_OFF);
  int*   start    = (int*)(ws + START_OFF);
  int*   alist    = (int*)(ws + ALIST_OFF);
  int*   bsum     = (int*)(ws + BSUM_OFF);
  int*   startb   = (int*)(ws + STARTB_OFF);
  int*   blist    = (int*)(ws + BLIST_OFF);
  int*   dlist    = (int*)(ws + DLIST_OFF);
  int*   bsumb    = (int*)(ws + BSUMB_OFF);
  int*   startp   = (int*)(ws + STARTP_OFF);
  int*   plist    = (int*)(ws + PLIST_OFF);
  int*   ilist    = (int*)(ws + ILIST_OFF);
  int*   bsump    = (int*)(ws + BSUMP_OFF);
  int*   desc1    = (int*)(ws + DESC1_OFF);
  int*   desc2    = (int*)(ws + DESC2_OFF);
  unsigned short* hbuf  = (unsigned short*)(ws + H_OFF);
  unsigned short* h2buf = (unsigned short*)(ws + H2_OFF);
  unsigned short* comb  = (unsigned short*)(ws + COMB_OFF);
  s16x8* wt_bm = (s16x8*)(ws + WT_BM_OFF);
  s16x8* wt_sc = (s16x8*)(ws + WT_SC_OFF);
  s16x8* wt1   = (s16x8*)(ws + WT1_OFF);
  s16x8* wt2   = (s16x8*)(ws + WT2_OFF);

  // Zero exactly what needs zeroing (agg, agg2, cnt/fill arrays) with our own
  // kernel -- the hipMemsetAsync fill dispatch measured 1.6 GB / ~240 us.
  k_zero<<<2048, 256, 0, stream>>>((uint4*)ws, ZERO_BYTES / 16);

  k_prep_w<<<8, 256, 0, stream>>>(W_bm, wt_bm);
  k_prep_w<<<8, 256, 0, stream>>>(W_sc, wt_sc);
  k_prep_w<<<8, 256, 0, stream>>>(W1, wt1);
  k_prep_w<<<8, 256, 0, stream>>>(W2, wt2);

  const int NSB_ANG  = (NBONDS + SCAN_EPB - 1) / SCAN_EPB;
  const int NSB_ATOM = (NATOMS + SCAN_EPB - 1) / SCAN_EPB;

  // CSR 1: angles -> bonds
  k_hist<<<(NANG + 255) / 256, 256, 0, stream>>>(ang_idx, NANG, 1, 0, cnt);
  k_scan1<<<NSB_ANG, 256, 0, stream>>>(cnt, start, bsum, NBONDS);
  k_scan2<<<1, 512, 0, stream>>>(bsum, NSB_ANG);
  k_scan_add<<<(NBONDS + 255) / 256, 256, 0, stream>>>(start, bsum, NBONDS);
  k_fill<<<(NANG + 255) / 256, 256, 0, stream>>>(ang_idx, NANG, 1, 0, start, fill, alist, (int*)nullptr);

  // CSR 2: bonds sorted by dst
  k_hist<<<(NBONDS + 255) / 256, 256, 0, stream>>>(bond_idx, NBONDS, 2, 1, cntb);
  k_scan1<<<NSB_ATOM, 256, 0, stream>>>(cntb, startb, bsumb, NATOMS);
  k_scan2<<<1, 512, 0, stream>>>(bsumb, NSB_ATOM);
  k_scan_add<<<(NATOMS + 255) / 256, 256, 0, stream>>>(startb, bsumb, NATOMS);
  k_fill<<<(NBONDS + 255) / 256, 256, 0, stream>>>(bond_idx, NBONDS, 2, 1, startb, fillb, blist, dlist);

  // CSR 3: pairs sorted by i
  k_hist<<<(NPAIRS + 255) / 256, 256, 0, stream>>>(sc_idx, NPAIRS, 2, 0, cntp);
  k_scan1<<<NSB_ATOM, 256, 0, stream>>>(cntp, startp, bsump, NATOMS);
  k_scan2<<<1, 512, 0, stream>>>(bsump, NSB_ATOM);
  k_scan_add<<<(NATOMS + 255) / 256, 256, 0, stream>>>(startp, bsump, NATOMS);
  k_fill<<<(NPAIRS + 255) / 256, 256, 0, stream>>>(sc_idx, NPAIRS, 2, 0, startp, fillp, plist, ilist);

  // Pack descriptors
  k_packb<<<(NBONDS + 255) / 256, 256, 0, stream>>>(blist, bond_idx, start, cnt, alist, desc1);
  k_packp<<<(NPAIRS + 255) / 256, 256, 0, stream>>>(plist, ilist, sc_idx, desc2);

  k_ln<<<NATOMS / 4, 256, 0, stream>>>(x, ln1w, ln1b, hbuf);

  // msg1 split: gather -> comb, then GEMM+scatter -> agg
  k_gather1<<<NBONDS * 16 / 256, 256, 0, stream>>>(hbuf, bond_x, angles, alist, desc1, comb);
  k_gemm_scatter<<<2048, 256, 0, stream>>>(comb, dlist, wt_bm, agg);
  k_update1<<<1024, 256, 0, stream>>>(agg, x, b1, ln2w, ln2b, wt1, out, h2buf);

  // msg2 split: gather -> comb (reused), then GEMM+scatter -> agg2
  k_gather2<<<NPAIRS * 16 / 256, 256, 0, stream>>>(h2buf, sc_pair, desc2, comb);
  k_gemm_scatter<<<2048, 256, 0, stream>>>(comb, ilist, wt_sc, agg2);
  k_update2<<<1024, 256, 0, stream>>>(agg2, b2, wt2, out);
}

// Round 10
// 745.256 us; speedup vs baseline: 1.0243x; 1.0243x over previous
//
#include <hip/hip_runtime.h>

#define SZ 128
#define NATOMS 100000
#define NBONDS 400000
#define NPAIRS 400000
#define NANG   800000

typedef float f32x4 __attribute__((ext_vector_type(4)));
typedef short s16x8 __attribute__((ext_vector_type(8)));

__device__ __forceinline__ unsigned short f2bf(float f) {
  union { float f; unsigned u; } v; v.f = f;
  unsigned r = v.u + 0x7FFFu + ((v.u >> 16) & 1u);
  return (unsigned short)(r >> 16);
}
__device__ __forceinline__ float bf2f(unsigned short h) {
  union { unsigned u; float f; } v; v.u = ((unsigned)h) << 16;
  return v.f;
}

// ---- workspace layout (bytes) ----
#define AGG_OFF      0ull
#define AGG2_OFF     51200000ull
#define CNT_OFF      102400000ull
#define FILL_OFF     104000000ull
#define CNTB_OFF     105600000ull
#define FILLB_OFF    106000000ull
#define CNTP_OFF     106400000ull
#define FILLP_OFF    106800000ull
#define ZERO_BYTES   107200000ull
#define START_OFF    107200000ull
#define ALIST_OFF    108800000ull
#define BSUM_OFF     112000000ull
#define STARTB_OFF   112004096ull
#define BLIST_OFF    112404096ull
#define DLIST_OFF    114004096ull
#define BSUMB_OFF    115604096ull
#define STARTP_OFF   115608192ull
#define PLIST_OFF    116008192ull
#define ILIST_OFF    117608192ull
#define BSUMP_OFF    119208192ull
#define DESC1_OFF    119212288ull   // 400K x 32B
#define DESC2_OFF    132012288ull   // 400K x 16B
#define H_OFF        138412288ull
#define H2_OFF       164012288ull
#define WT_BM_OFF    189612288ull
#define WT_SC_OFF    (WT_BM_OFF + 32768ull)
#define WT1_OFF      (WT_SC_OFF + 32768ull)
#define WT2_OFF      (WT1_OFF + 32768ull)
#define COMB_OFF     189744128ull   // 400K x 256B bf16 (shared by msg1/msg2)

#define SCAN_EPB 1024
#define NSB_ANG  ((NBONDS + SCAN_EPB - 1) / SCAN_EPB)   // 391
#define NSB_ATOM ((NATOMS + SCAN_EPB - 1) / SCAN_EPB)   // 98

// Zero exactly ZERO_BYTES of ws with wide stores.
__global__ __launch_bounds__(256) void k_zero(uint4* __restrict__ p, size_t n16) {
  size_t id = (size_t)blockIdx.x * 256 + threadIdx.x;
  size_t stride = (size_t)gridDim.x * 256;
  uint4 z = {0u, 0u, 0u, 0u};
  for (size_t i = id; i < n16; i += stride) p[i] = z;
}

// Pack all 4 W matrices (f32 [k][n]) into bf16 B-fragment order in one dispatch.
__global__ __launch_bounds__(256) void k_prep_w4(const float* __restrict__ W0,
                                                 const float* __restrict__ W1,
                                                 const float* __restrict__ W2,
                                                 const float* __restrict__ W3,
                                                 s16x8* __restrict__ T0,
                                                 s16x8* __restrict__ T1,
                                                 s16x8* __restrict__ T2,
                                                 s16x8* __restrict__ T3) {
  int gid = blockIdx.x * 256 + threadIdx.x;   // 0..8191
  int m = gid >> 11, cid = gid & 2047;
  const float* W = (m == 0) ? W0 : (m == 1) ? W1 : (m == 2) ? W2 : W3;
  s16x8* Wt = (m == 0) ? T0 : (m == 1) ? T1 : (m == 2) ? T2 : T3;
  int nt8 = cid >> 8, kk = (cid >> 6) & 3, l = cid & 63;
  int col = nt8 * 16 + (l & 15);
  int k0  = kk * 32 + (l >> 4) * 8;
  s16x8 v;
#pragma unroll
  for (int i = 0; i < 8; ++i) v[i] = (short)f2bf(W[(k0 + i) * SZ + col]);
  Wt[cid] = v;
}

// LayerNorm f32 -> bf16
__global__ __launch_bounds__(256) void k_ln(const float* __restrict__ x,
                                            const float* __restrict__ g,
                                            const float* __restrict__ bvec,
                                            unsigned short* __restrict__ hout) {
  int row  = blockIdx.x * 4 + (threadIdx.x >> 6);
  int lane = threadIdx.x & 63;
  float2 v = *(const float2*)(x + (size_t)row * SZ + lane * 2);
  float s = v.x + v.y, sq = v.x * v.x + v.y * v.y;
#pragma unroll
  for (int off = 32; off; off >>= 1) { s += __shfl_xor(s, off); sq += __shfl_xor(sq, off); }
  float m = s * 0.0078125f;
  float var = sq * 0.0078125f - m * m;
  float rstd = rsqrtf(var + 1e-5f);
  float2 gv = *(const float2*)(g + lane * 2);
  float2 bv = *(const float2*)(bvec + lane * 2);
  float y0 = (v.x - m) * rstd * gv.x + bv.x;
  float y1 = (v.y - m) * rstd * gv.y + bv.y;
  unsigned pack = (unsigned)f2bf(y0) | ((unsigned)f2bf(y1) << 16);
  ((unsigned*)hout)[(size_t)row * 64 + lane] = pack;
}

// ---- batched CSR build ----
// hist for all three keys in one dispatch
__global__ __launch_bounds__(256) void k_hist3(const int* __restrict__ aidx,
                                               const int* __restrict__ bidx,
                                               const int* __restrict__ sidx,
                                               int* __restrict__ cnt,
                                               int* __restrict__ cntb,
                                               int* __restrict__ cntp) {
  int id = blockIdx.x * 256 + threadIdx.x;
  if (id < NANG) {
    atomicAdd(&cnt[aidx[id]], 1);
  } else if (id < NANG + NBONDS) {
    int b = id - NANG;
    atomicAdd(&cntb[bidx[2 * b + 1]], 1);
  } else if (id < NANG + NBONDS + NPAIRS) {
    int p = id - NANG - NBONDS;
    atomicAdd(&cntp[sidx[2 * p]], 1);
  }
}

// ranged per-block scan over three arrays in one dispatch
__global__ __launch_bounds__(256) void k_scan1_3(const int* __restrict__ c0, int* __restrict__ s0, int* __restrict__ b0,
                                                 const int* __restrict__ c1, int* __restrict__ s1, int* __restrict__ b1,
                                                 const int* __restrict__ c2, int* __restrict__ s2, int* __restrict__ b2) {
  __shared__ int wsum[4];
  int bid = blockIdx.x;
  const int* cnt; int* start; int* bsum; int N; int lb;
  if (bid < NSB_ANG)                  { cnt = c0; start = s0; bsum = b0; N = NBONDS; lb = bid; }
  else if (bid < NSB_ANG + NSB_ATOM)  { cnt = c1; start = s1; bsum = b1; N = NATOMS; lb = bid - NSB_ANG; }
  else                                { cnt = c2; start = s2; bsum = b2; N = NATOMS; lb = bid - NSB_ANG - NSB_ATOM; }
  int tid = threadIdx.x;
  int base = lb * SCAN_EPB + tid * 4;
  int4 c;
  if (base + 3 < N) {
    c = *(const int4*)(cnt + base);
  } else {
    c.x = (base + 0 < N) ? cnt[base + 0] : 0;
    c.y = (base + 1 < N) ? cnt[base + 1] : 0;
    c.z = (base + 2 < N) ? cnt[base + 2] : 0;
    c.w = (base + 3 < N) ? cnt[base + 3] : 0;
  }
  int tsum = c.x + c.y + c.z + c.w;
  int lane = tid & 63, wid = tid >> 6;
  int inc = tsum;
#pragma unroll
  for (int off = 1; off < 64; off <<= 1) {
    int o = __shfl_up(inc, off);
    if (lane >= off) inc += o;
  }
  if (lane == 63) wsum[wid] = inc;
  __syncthreads();
  int woff = 0;
#pragma unroll
  for (int wq = 0; wq < 4; ++wq) { if (wq < wid) woff += wsum[wq]; }
  int s = woff + inc - tsum;
  if (base + 0 < N) { start[base + 0] = s; } s += c.x;
  if (base + 1 < N) { start[base + 1] = s; } s += c.y;
  if (base + 2 < N) { start[base + 2] = s; } s += c.z;
  if (base + 3 < N) { start[base + 3] = s; }
  if (tid == 255) {
    int tot = 0;
#pragma unroll
    for (int wq = 0; wq < 4; ++wq) tot += wsum[wq];
    bsum[lb] = tot;
  }
}

// three single-block scans in one dispatch (block b -> array b)
__global__ __launch_bounds__(512) void k_scan2_3(int* __restrict__ b0,
                                                 int* __restrict__ b1,
                                                 int* __restrict__ b2) {
  __shared__ int tmp[2][512];
  int* bsum; int n;
  if (blockIdx.x == 0)      { bsum = b0; n = NSB_ANG; }
  else if (blockIdx.x == 1) { bsum = b1; n = NSB_ATOM; }
  else                      { bsum = b2; n = NSB_ATOM; }
  int tid = threadIdx.x;
  tmp[0][tid] = (tid < n) ? bsum[tid] : 0;
  int pi = 0;
  for (int off = 1; off < 512; off <<= 1) {
    __syncthreads();
    int t = tmp[pi][tid];
    if (tid >= off) t += tmp[pi][tid - off];
    tmp[pi ^ 1][tid] = t;
    pi ^= 1;
  }
  __syncthreads();
  if (tid < n) bsum[tid] = (tid == 0) ? 0 : tmp[pi][tid - 1];
}

__global__ __launch_bounds__(256) void k_scan_add3(int* __restrict__ s0, const int* __restrict__ b0,
                                                   int* __restrict__ s1, const int* __restrict__ b1,
                                                   int* __restrict__ s2, const int* __restrict__ b2) {
  int id = blockIdx.x * 256 + threadIdx.x;
  if (id < NBONDS) {
    s0[id] += b0[id / SCAN_EPB];
  } else if (id < NBONDS + NATOMS) {
    int k = id - NBONDS;
    s1[k] += b1[k / SCAN_EPB];
  } else if (id < NBONDS + 2 * NATOMS) {
    int k = id - NBONDS - NATOMS;
    s2[k] += b2[k / SCAN_EPB];
  }
}

__global__ __launch_bounds__(256) void k_fill3(const int* __restrict__ aidx,
                                               const int* __restrict__ bidx,
                                               const int* __restrict__ sidx,
                                               const int* __restrict__ start, int* __restrict__ fill, int* __restrict__ alist,
                                               const int* __restrict__ startb, int* __restrict__ fillb, int* __restrict__ blist, int* __restrict__ dlist,
                                               const int* __restrict__ startp, int* __restrict__ fillp, int* __restrict__ plist, int* __restrict__ ilist) {
  int id = blockIdx.x * 256 + threadIdx.x;
  if (id < NANG) {
    int k = aidx[id];
    int p = atomicAdd(&fill[k], 1);
    alist[start[k] + p] = id;
  } else if (id < NANG + NBONDS) {
    int b = id - NANG;
    int k = bidx[2 * b + 1];
    int p = atomicAdd(&fillb[k], 1);
    int pos = startb[k] + p;
    blist[pos] = b;
    dlist[pos] = k;
  } else if (id < NANG + NBONDS + NPAIRS) {
    int q = id - NANG - NBONDS;
    int k = sidx[2 * q];
    int p = atomicAdd(&fillp[k], 1);
    int pos = startp[k] + p;
    plist[pos] = q;
    ilist[pos] = k;
  }
}

// pack both descriptor streams in one dispatch (each thread does one pos of each)
__global__ __launch_bounds__(256) void k_pack(const int* __restrict__ blist,
                                              const int* __restrict__ bidx,
                                              const int* __restrict__ start,
                                              const int* __restrict__ cnt,
                                              const int* __restrict__ alist,
                                              int* __restrict__ desc1,
                                              const int* __restrict__ plist,
                                              const int* __restrict__ ilist,
                                              const int* __restrict__ sidx,
                                              int* __restrict__ desc2) {
  int pos = blockIdx.x * 256 + threadIdx.x;
  if (pos >= NBONDS) return;   // NBONDS == NPAIRS
  {
    int b = blist[pos];
    int4 dA, dB;
    dA.x = b;
    dA.y = bidx[2 * b];
    int s0 = start[b];
    int nc = cnt[b];
    dA.z = s0;
    dA.w = nc;
    dB.x = (0 < nc) ? alist[s0 + 0] : 0;
    dB.y = (1 < nc) ? alist[s0 + 1] : 0;
    dB.z = (2 < nc) ? alist[s0 + 2] : 0;
    dB.w = (3 < nc) ? alist[s0 + 3] : 0;
    *(int4*)(desc1 + (size_t)pos * 8)     = dA;
    *(int4*)(desc1 + (size_t)pos * 8 + 4) = dB;
  }
  {
    int b = plist[pos];
    int4 d;
    d.x = b;
    d.y = ilist[pos];
    d.z = sidx[2 * b + 1];
    d.w = 0;
    *(int4*)(desc2 + (size_t)pos * 4) = d;
  }
}

// Pass A1: comb[pos] = bf16(h[src] + bond_x[b] + sum(angles)) -- streaming gather.
// Single-use streams (bond_x, angles) use nontemporal loads to avoid thrashing
// L2 shared with the reused h rows (25MB bf16, cache-resident).
__global__ __launch_bounds__(256) void k_gather1(const unsigned short* __restrict__ h,
                                                 const float* __restrict__ bx,
                                                 const float* __restrict__ angles,
                                                 const int* __restrict__ alist,
                                                 const int* __restrict__ desc,
                                                 unsigned short* __restrict__ comb) {
  int id = blockIdx.x * 256 + threadIdx.x;   // NBONDS*16 threads exactly
  int pos = id >> 4, kc = id & 15;
  int4 dA = *(const int4*)(desc + (size_t)pos * 8);
  int4 dB = *(const int4*)(desc + (size_t)pos * 8 + 4);
  int b = dA.x, src = dA.y, s0 = dA.z, nc = dA.w;
  const int co = kc * 8;
  f32x4 a0 = __builtin_nontemporal_load((const f32x4*)(bx + (size_t)b * SZ + co));
  f32x4 a1 = __builtin_nontemporal_load((const f32x4*)(bx + (size_t)b * SZ + co + 4));
  uint4 hv = *(const uint4*)(h + (size_t)src * SZ + co);
  int aj[4] = {dB.x, dB.y, dB.z, dB.w};
#pragma unroll
  for (int t = 0; t < 4; ++t) {
    if (t < nc) {
      const f32x4* ap = (const f32x4*)(angles + (size_t)aj[t] * SZ + co);
      f32x4 u0 = __builtin_nontemporal_load(ap);
      f32x4 u1 = __builtin_nontemporal_load(ap + 1);
      a0 += u0; a1 += u1;
    }
  }
  for (int t = 4; t < nc; ++t) {
    int ar = alist[s0 + t];
    const f32x4* ap = (const f32x4*)(angles + (size_t)ar * SZ + co);
    f32x4 u0 = __builtin_nontemporal_load(ap);
    f32x4 u1 = __builtin_nontemporal_load(ap + 1);
    a0 += u0; a1 += u1;
  }
  const unsigned short* hp = (const unsigned short*)&hv;
  uint4 r;
  unsigned* rp = (unsigned*)&r;
#pragma unroll
  for (int i = 0; i < 2; ++i) {
    unsigned lo = f2bf(bf2f(hp[2 * i]) + a0[2 * i]);
    unsigned hi = f2bf(bf2f(hp[2 * i + 1]) + a0[2 * i + 1]);
    rp[i] = lo | (hi << 16);
  }
#pragma unroll
  for (int i = 0; i < 2; ++i) {
    unsigned lo = f2bf(bf2f(hp[4 + 2 * i]) + a1[2 * i]);
    unsigned hi = f2bf(bf2f(hp[4 + 2 * i + 1]) + a1[2 * i + 1]);
    rp[2 + i] = lo | (hi << 16);
  }
  *(uint4*)(comb + (size_t)pos * SZ + co) = r;
}

// Pass A2: comb[pos] = bf16(h2[i] + h2[j] + sc_pair[b])
__global__ __launch_bounds__(256) void k_gather2(const unsigned short* __restrict__ h2,
                                                 const float* __restrict__ scp,
                                                 const int* __restrict__ desc,
                                                 unsigned short* __restrict__ comb) {
  int id = blockIdx.x * 256 + threadIdx.x;   // NPAIRS*16 threads exactly
  int pos = id >> 4, kc = id & 15;
  int4 d = *(const int4*)(desc + (size_t)pos * 4);
  int b = d.x, i0 = d.y, j0 = d.z;
  const int co = kc * 8;
  f32x4 a0 = __builtin_nontemporal_load((const f32x4*)(scp + (size_t)b * SZ + co));
  f32x4 a1 = __builtin_nontemporal_load((const f32x4*)(scp + (size_t)b * SZ + co + 4));
  uint4 hv1 = *(const uint4*)(h2 + (size_t)i0 * SZ + co);
  uint4 hv2 = *(const uint4*)(h2 + (size_t)j0 * SZ + co);
  const unsigned short* p1 = (const unsigned short*)&hv1;
  const unsigned short* p2 = (const unsigned short*)&hv2;
  uint4 r;
  unsigned* rp = (unsigned*)&r;
#pragma unroll
  for (int i = 0; i < 2; ++i) {
    unsigned lo = f2bf(bf2f(p1[2 * i]) + bf2f(p2[2 * i]) + a0[2 * i]);
    unsigned hi = f2bf(bf2f(p1[2 * i + 1]) + bf2f(p2[2 * i + 1]) + a0[2 * i + 1]);
    rp[i] = lo | (hi << 16);
  }
#pragma unroll
  for (int i = 0; i < 2; ++i) {
    unsigned lo = f2bf(bf2f(p1[4 + 2 * i]) + bf2f(p2[4 + 2 * i]) + a1[2 * i]);
    unsigned hi = f2bf(bf2f(p1[4 + 2 * i + 1]) + bf2f(p2[4 + 2 * i + 1]) + a1[2 * i + 1]);
    rp[2 + i] = lo | (hi << 16);
  }
  *(uint4*)(comb + (size_t)pos * SZ + co) = r;
}

// Pass B: dense GEMM over sorted comb rows + run-combined relu atomic scatter.
__global__ __launch_bounds__(256) void k_gemm_scatter(const unsigned short* __restrict__ comb,
                                                      const int* __restrict__ klist,
                                                      const s16x8* __restrict__ Wt,
                                                      float* __restrict__ aggout) {
  __shared__ s16x8 Wl[2048];   // 32KB B-fragment order
  int tid = threadIdx.x;
  for (int i = tid; i < 2048; i += 256) Wl[i] = Wt[i];
  __syncthreads();
  int w = tid >> 6, l = tid & 63;
  int grp = l >> 4;
  int rl  = l & 15;
  int gw = blockIdx.x * 4 + w;
  int nw = gridDim.x * 4;
  for (int tile = gw; tile < NBONDS / 16; tile += nw) {
    int base = tile * 16;
    f32x4 acc[8];
#pragma unroll
    for (int nb = 0; nb < 8; ++nb) acc[nb] = (f32x4){0.f, 0.f, 0.f, 0.f};
#pragma unroll
    for (int kk = 0; kk < 4; ++kk) {
      const int co = kk * 32 + grp * 8;
      s16x8 av = *(const s16x8*)(comb + (size_t)(base + rl) * SZ + co);
#pragma unroll
      for (int nb = 0; nb < 8; ++nb)
        acc[nb] = __builtin_amdgcn_mfma_f32_16x16x32_bf16(av, Wl[(nb * 4 + kk) * 64 + l], acc[nb], 0, 0, 0);
    }
    int4 dv = *(const int4*)(klist + base + grp * 4);
    int dn[4] = {dv.x, dv.y, dv.z, dv.w};
    float v[8];
#pragma unroll
    for (int nb = 0; nb < 8; ++nb) v[nb] = fmaxf(acc[nb][0], 0.f);
    int dprev = dn[0];
#pragma unroll
    for (int p = 1; p < 4; ++p) {
      if (dn[p] == dprev) {
#pragma unroll
        for (int nb = 0; nb < 8; ++nb) v[nb] += fmaxf(acc[nb][p], 0.f);
      } else {
        float* pb = aggout + (size_t)dprev * SZ + rl;
#pragma unroll
        for (int nb = 0; nb < 8; ++nb) unsafeAtomicAdd(pb + nb * 16, v[nb]);
#pragma unroll
        for (int nb = 0; nb < 8; ++nb) v[nb] = fmaxf(acc[nb][p], 0.f);
        dprev = dn[p];
      }
    }
    float* pb = aggout + (size_t)dprev * SZ + rl;
#pragma unroll
    for (int nb = 0; nb < 8; ++nb) unsafeAtomicAdd(pb + nb * 16, v[nb]);
  }
}

// update1: out = x + agg@W1 + b1 ; h2 = LN(out)
__global__ __launch_bounds__(256) void k_update1(const float* __restrict__ agg,
                                                 const float* __restrict__ x,
                                                 const float* __restrict__ b1,
                                                 const float* __restrict__ lnw,
                                                 const float* __restrict__ lnb,
                                                 const s16x8* __restrict__ Wt,
                                                 float* __restrict__ out,
                                                 unsigned short* __restrict__ h2) {
  __shared__ s16x8 Wl[2048];
  __shared__ s16x8 Tl[256];
  __shared__ float Xl[16][128];
  int tid = threadIdx.x;
  for (int i = tid; i < 2048; i += 256) Wl[i] = Wt[i];
  __syncthreads();
  int r = tid >> 4, kc = tid & 15;
  int w = tid >> 6, l = tid & 63;
  int colb = w * 32 + (l & 15);
  int rowb = (l >> 4) * 4;
  float bb0 = b1[colb], bb1 = b1[colb + 16];
  float2 g2 = *(const float2*)(lnw + l * 2);
  float2 be2 = *(const float2*)(lnb + l * 2);
  for (int tile = blockIdx.x; tile < NATOMS / 16; tile += gridDim.x) {
    int base = tile * 16;
    int a = base + r;
    float qb[8];
    *(float4*)&qb[0] = *(const float4*)(agg + (size_t)a * SZ + kc * 8);
    *(float4*)&qb[4] = *(const float4*)(agg + (size_t)a * SZ + kc * 8 + 4);
    s16x8 tv;
#pragma unroll
    for (int i = 0; i < 8; ++i) tv[i] = (short)f2bf(qb[i]);
    Tl[(kc >> 2) * 64 + (kc & 3) * 16 + r] = tv;
    __syncthreads();
    f32x4 acc0 = {0.f, 0.f, 0.f, 0.f}, acc1 = {0.f, 0.f, 0.f, 0.f};
#pragma unroll
    for (int kk = 0; kk < 4; ++kk) {
      s16x8 av = Tl[kk * 64 + l];
      acc0 = __builtin_amdgcn_mfma_f32_16x16x32_bf16(av, Wl[((w * 2 + 0) * 4 + kk) * 64 + l], acc0, 0, 0, 0);
      acc1 = __builtin_amdgcn_mfma_f32_16x16x32_bf16(av, Wl[((w * 2 + 1) * 4 + kk) * 64 + l], acc1, 0, 0, 0);
    }
#pragma unroll
    for (int p = 0; p < 4; ++p) {
      int atom = base + rowb + p;
      float v0 = acc0[p] + bb0 + x[(size_t)atom * SZ + colb];
      float v1 = acc1[p] + bb1 + x[(size_t)atom * SZ + colb + 16];
      out[(size_t)atom * SZ + colb] = v0;
      out[(size_t)atom * SZ + colb + 16] = v1;
      Xl[rowb + p][colb] = v0;
      Xl[rowb + p][colb + 16] = v1;
    }
    __syncthreads();
#pragma unroll
    for (int rr = 0; rr < 4; ++rr) {
      int rw = w * 4 + rr;
      float2 v = *(const float2*)&Xl[rw][l * 2];
      float s = v.x + v.y, sq = v.x * v.x + v.y * v.y;
#pragma unroll
      for (int off = 32; off; off >>= 1) { s += __shfl_xor(s, off); sq += __shfl_xor(sq, off); }
      float m = s * 0.0078125f;
      float var = sq * 0.0078125f - m * m;
      float rstd = rsqrtf(var + 1e-5f);
      float y0 = (v.x - m) * rstd * g2.x + be2.x;
      float y1 = (v.y - m) * rstd * g2.y + be2.y;
      unsigned pack = (unsigned)f2bf(y0) | ((unsigned)f2bf(y1) << 16);
      ((unsigned*)h2)[(size_t)(base + rw) * 64 + l] = pack;
    }
    __syncthreads();
  }
}

// update2: out += agg2@W2 + b2
__global__ __launch_bounds__(256) void k_update2(const float* __restrict__ agg2,
                                                 const float* __restrict__ b2,
                                                 const s16x8* __restrict__ Wt,
                                                 float* __restrict__ out) {
  __shared__ s16x8 Wl[2048];
  __shared__ s16x8 Tl[256];
  int tid = threadIdx.x;
  for (int i = tid; i < 2048; i += 256) Wl[i] = Wt[i];
  __syncthreads();
  int r = tid >> 4, kc = tid & 15;
  int w = tid >> 6, l = tid & 63;
  int colb = w * 32 + (l & 15);
  int rowb = (l >> 4) * 4;
  float bb0 = b2[colb], bb1 = b2[colb + 16];
  for (int tile = blockIdx.x; tile < NATOMS / 16; tile += gridDim.x) {
    int base = tile * 16;
    int a = base + r;
    float qb[8];
    *(float4*)&qb[0] = *(const float4*)(agg2 + (size_t)a * SZ + kc * 8);
    *(float4*)&qb[4] = *(const float4*)(agg2 + (size_t)a * SZ + kc * 8 + 4);
    s16x8 tv;
#pragma unroll
    for (int i = 0; i < 8; ++i) tv[i] = (short)f2bf(qb[i]);
    Tl[(kc >> 2) * 64 + (kc & 3) * 16 + r] = tv;
    __syncthreads();
    f32x4 acc0 = {0.f, 0.f, 0.f, 0.f}, acc1 = {0.f, 0.f, 0.f, 0.f};
#pragma unroll
    for (int kk = 0; kk < 4; ++kk) {
      s16x8 av = Tl[kk * 64 + l];
      acc0 = __builtin_amdgcn_mfma_f32_16x16x32_bf16(av, Wl[((w * 2 + 0) * 4 + kk) * 64 + l], acc0, 0, 0, 0);
      acc1 = __builtin_amdgcn_mfma_f32_16x16x32_bf16(av, Wl[((w * 2 + 1) * 4 + kk) * 64 + l], acc1, 0, 0, 0);
    }
#pragma unroll
    for (int p = 0; p < 4; ++p) {
      int atom = base + rowb + p;
      out[(size_t)atom * SZ + colb]      += acc0[p] + bb0;
      out[(size_t)atom * SZ + colb + 16] += acc1[p] + bb1;
    }
    __syncthreads();
  }
}

extern "C" void kernel_launch(void* const* d_in, const int* in_sizes, int n_in,
                              void* d_out, int out_size, void* d_ws, size_t ws_size,
                              hipStream_t stream) {
  (void)in_sizes; (void)n_in; (void)out_size; (void)ws_size;
  const float* x        = (const float*)d_in[0];
  const float* bond_x   = (const float*)d_in[1];
  const float* sc_pair  = (const float*)d_in[2];
  const float* angles   = (const float*)d_in[3];
  const float* W_bm     = (const float*)d_in[4];
  const float* W_sc     = (const float*)d_in[5];
  const float* W1       = (const float*)d_in[6];
  const float* b1       = (const float*)d_in[7];
  const float* W2       = (const float*)d_in[8];
  const float* b2       = (const float*)d_in[9];
  const float* ln1w     = (const float*)d_in[10];
  const float* ln1b     = (const float*)d_in[11];
  const float* ln2w     = (const float*)d_in[12];
  const float* ln2b     = (const float*)d_in[13];
  const int* bond_idx   = (const int*)d_in[15];
  const int* sc_idx     = (const int*)d_in[16];
  const int* ang_idx    = (const int*)d_in[17];
  float* out = (float*)d_out;
  char* ws = (char*)d_ws;

  float* agg      = (float*)(ws + AGG_OFF);
  float* agg2     = (float*)(ws + AGG2_OFF);
  int*   cnt      = (int*)(ws + CNT_OFF);
  int*   fill     = (int*)(ws + FILL_OFF);
  int*   cntb     = (int*)(ws + CNTB_OFF);
  int*   fillb    = (int*)(ws + FILLB_OFF);
  int*   cntp     = (int*)(ws + CNTP_OFF);
  int*   fillp    = (int*)(ws + FILLP_OFF);
  int*   start    = (int*)(ws + START_OFF);
  int*   alist    = (int*)(ws + ALIST_OFF);
  int*   bsum     = (int*)(ws + BSUM_OFF);
  int*   startb   = (int*)(ws + STARTB_OFF);
  int*   blist    = (int*)(ws + BLIST_OFF);
  int*   dlist    = (int*)(ws + DLIST_OFF);
  int*   bsumb    = (int*)(ws + BSUMB_OFF);
  int*   startp   = (int*)(ws + STARTP_OFF);
  int*   plist    = (int*)(ws + PLIST_OFF);
  int*   ilist    = (int*)(ws + ILIST_OFF);
  int*   bsump    = (int*)(ws + BSUMP_OFF);
  int*   desc1    = (int*)(ws + DESC1_OFF);
  int*   desc2    = (int*)(ws + DESC2_OFF);
  unsigned short* hbuf  = (unsigned short*)(ws + H_OFF);
  unsigned short* h2buf = (unsigned short*)(ws + H2_OFF);
  unsigned short* comb  = (unsigned short*)(ws + COMB_OFF);
  s16x8* wt_bm = (s16x8*)(ws + WT_BM_OFF);
  s16x8* wt_sc = (s16x8*)(ws + WT_SC_OFF);
  s16x8* wt1   = (s16x8*)(ws + WT1_OFF);
  s16x8* wt2   = (s16x8*)(ws + WT2_OFF);

  k_zero<<<2048, 256, 0, stream>>>((uint4*)ws, ZERO_BYTES / 16);
  k_prep_w4<<<32, 256, 0, stream>>>(W_bm, W_sc, W1, W2, wt_bm, wt_sc, wt1, wt2);

  // Batched CSR build (3 keys in one chain)
  k_hist3<<<(NANG + NBONDS + NPAIRS + 255) / 256, 256, 0, stream>>>(ang_idx, bond_idx, sc_idx, cnt, cntb, cntp);
  k_scan1_3<<<NSB_ANG + 2 * NSB_ATOM, 256, 0, stream>>>(cnt, start, bsum, cntb, startb, bsumb, cntp, startp, bsump);
  k_scan2_3<<<3, 512, 0, stream>>>(bsum, bsumb, bsump);
  k_scan_add3<<<(NBONDS + 2 * NATOMS + 255) / 256, 256, 0, stream>>>(start, bsum, startb, bsumb, startp, bsump);
  k_fill3<<<(NANG + NBONDS + NPAIRS + 255) / 256, 256, 0, stream>>>(ang_idx, bond_idx, sc_idx,
                                                                    start, fill, alist,
                                                                    startb, fillb, blist, dlist,
                                                                    startp, fillp, plist, ilist);
  k_pack<<<(NBONDS + 255) / 256, 256, 0, stream>>>(blist, bond_idx, start, cnt, alist, desc1,
                                                   plist, ilist, sc_idx, desc2);

  k_ln<<<NATOMS / 4, 256, 0, stream>>>(x, ln1w, ln1b, hbuf);

  // msg1 split: gather -> comb, then GEMM+scatter -> agg
  k_gather1<<<NBONDS * 16 / 256, 256, 0, stream>>>(hbuf, bond_x, angles, alist, desc1, comb);
  k_gemm_scatter<<<2048, 256, 0, stream>>>(comb, dlist, wt_bm, agg);
  k_update1<<<1024, 256, 0, stream>>>(agg, x, b1, ln2w, ln2b, wt1, out, h2buf);

  // msg2 split: gather -> comb (reused), then GEMM+scatter -> agg2
  k_gather2<<<NPAIRS * 16 / 256, 256, 0, stream>>>(h2buf, sc_pair, desc2, comb);
  k_gemm_scatter<<<2048, 256, 0, stream>>>(comb, ilist, wt_sc, agg2);
  k_update2<<<1024, 256, 0, stream>>>(agg2, b2, wt2, out);
}